// Round 1
// baseline (222.578 us; speedup 1.0000x reference)
//
#include <hip/hip_runtime.h>

// Joint bilateral filter 5x5, SAME zero padding.
// template: (1,3,1080,1920) f32 planar; vector: (1,2,1080,1920) f32 planar.
// out: (1,2,1080,1920) f32.
//
// Round 4: LDS-pressure / latency fix.
//  - 2 output rows per thread (tile 64x30): 6-row window read once feeds both
//    rows -> 9 b128 LDS reads/px instead of 12.5 b128 + 3 b32.
//  - center pixels extracted from b128 window reads (the stride-4 scalar
//    ds_read_b32 center loads were an 8-bank-clump conflict pattern).
//  - LDS row stride padded 68->76 dwords: row-to-row bank shift = 12, so the
//    wave's 4 row-groups land on bank offsets {0,24,16,8} (distinct).
//  - coeff = max(0.875 - 50*id, 0)  (id>=0 so the abs and upper clip fold away).
//  - 1080 blocks (exact tiling) -> half the barriers/staging rounds per pixel.

#define IMG_H 1080
#define IMG_W 1920
#define IMG_HW (IMG_H * IMG_W)
#define TS_X 64
#define TS_Y 30
#define HALO_H 34      // TS_Y + 4
#define HALO_W 68      // TS_X + 4: cols x0-2 .. x0+65 (all that is ever read)
#define LDS_W 76       // padded row stride (dwords); 16B-aligned, 12-bank shift/row
#define NCH 5
#define F4_PER_ROW 17            // 68/4
#define F4_PER_CH (F4_PER_ROW * HALO_H)   // 578

typedef float f4u __attribute__((ext_vector_type(4), aligned(4)));

__global__ __launch_bounds__(256, 3)
void jbf_kernel(const float* __restrict__ tpl,
                const float* __restrict__ vec,
                float* __restrict__ out) {
    constexpr float SIDIV = 50.0f;   // 1/(2*sigma_intensity^2)
    // coeff = clip(1 - |KVAL - id*SIDIV|, 0, 1), KVAL = -0.125, id >= 0
    //       = max(0.875 - 50*id, 0)

    __shared__ __align__(16) float smem[NCH][HALO_H][LDS_W];

    const int tid = threadIdx.x;
    const int bx = blockIdx.x, by = blockIdx.y;
    const int x0 = bx * TS_X;
    const int y0 = by * TS_Y;

    // interior: halo window (y0-2..y0+31, x0-2..x0+65) fully in-bounds
    const bool interior = (bx >= 1) & (bx <= 28) & (by >= 1) & (by <= 34);

    if (interior) {
        const int tl = (y0 - 2) * IMG_W + (x0 - 2);
        f4u v[15];
#pragma unroll
        for (int ch = 0; ch < NCH; ++ch) {
            const float* __restrict__ src =
                (ch < 3) ? (tpl + ch * IMG_HW) : (vec + (ch - 3) * IMG_HW);
#pragma unroll
            for (int it = 0; it < 3; ++it) {
                int idx = tid + it * 256;
                idx = (idx < F4_PER_CH) ? idx : 0;     // clamp, load always in-bounds
                const int r  = idx / F4_PER_ROW;
                const int c4 = idx - r * F4_PER_ROW;
                v[ch * 3 + it] = *(const f4u*)(src + tl + r * IMG_W + c4 * 4);
            }
        }
#pragma unroll
        for (int ch = 0; ch < NCH; ++ch) {
#pragma unroll
            for (int it = 0; it < 3; ++it) {
                const int idx = tid + it * 256;
                if (idx < F4_PER_CH) {
                    const int r  = idx / F4_PER_ROW;
                    const int c4 = idx - r * F4_PER_ROW;
                    float4* d = (float4*)&smem[ch][r][c4 * 4];
                    d->x = v[ch * 3 + it].x; d->y = v[ch * 3 + it].y;
                    d->z = v[ch * 3 + it].z; d->w = v[ch * 3 + it].w;
                }
            }
        }
    } else {
        // border: scalar bounds-checked staging with zero fill
#pragma unroll
        for (int c = 0; c < NCH; ++c) {
            const float* __restrict__ src =
                (c < 3) ? (tpl + c * IMG_HW) : (vec + (c - 3) * IMG_HW);
            for (int i = tid; i < HALO_H * HALO_W; i += 256) {
                const int r   = i / HALO_W;
                const int col = i - r * HALO_W;
                const int gy  = y0 + r - 2;
                const int gx  = x0 + col - 2;
                float val = 0.0f;
                if (gy >= 0 && gy < IMG_H && gx >= 0 && gx < IMG_W)
                    val = src[gy * IMG_W + gx];
                smem[c][r][col] = val;
            }
        }
    }
    __syncthreads();

    const int tx  = tid & 15;   // 16 threads across
    const int tyq = tid >> 4;   // 0..15; 15 compute rows used

    if (tyq < 15) {
        const int lx = tx * 4;        // halo col of first owned pixel
        const int rA = tyq * 2;       // window base row; outputs rA(+2), rA+1(+3) centers

        // centers for output rows A (halo row rA+2) and B (halo row rA+3)
        float cA0[4], cA1[4], cA2[4], cB0[4], cB1[4], cB2[4];
        {
            const float4 a0 = *(const float4*)&smem[0][rA + 2][lx];
            const float4 b0 = *(const float4*)&smem[0][rA + 2][lx + 4];
            const float4 a1 = *(const float4*)&smem[1][rA + 2][lx];
            const float4 b1 = *(const float4*)&smem[1][rA + 2][lx + 4];
            const float4 a2 = *(const float4*)&smem[2][rA + 2][lx];
            const float4 b2 = *(const float4*)&smem[2][rA + 2][lx + 4];
            cA0[0] = a0.z; cA0[1] = a0.w; cA0[2] = b0.x; cA0[3] = b0.y;
            cA1[0] = a1.z; cA1[1] = a1.w; cA1[2] = b1.x; cA1[3] = b1.y;
            cA2[0] = a2.z; cA2[1] = a2.w; cA2[2] = b2.x; cA2[3] = b2.y;
        }
        {
            const float4 a0 = *(const float4*)&smem[0][rA + 3][lx];
            const float4 b0 = *(const float4*)&smem[0][rA + 3][lx + 4];
            const float4 a1 = *(const float4*)&smem[1][rA + 3][lx];
            const float4 b1 = *(const float4*)&smem[1][rA + 3][lx + 4];
            const float4 a2 = *(const float4*)&smem[2][rA + 3][lx];
            const float4 b2 = *(const float4*)&smem[2][rA + 3][lx + 4];
            cB0[0] = a0.z; cB0[1] = a0.w; cB0[2] = b0.x; cB0[3] = b0.y;
            cB1[0] = a1.z; cB1[1] = a1.w; cB1[2] = b1.x; cB1[3] = b1.y;
            cB2[0] = a2.z; cB2[1] = a2.w; cB2[2] = b2.x; cB2[3] = b2.y;
        }

        float n0A[4] = {0.f, 0.f, 0.f, 0.f}, n1A[4] = {0.f, 0.f, 0.f, 0.f};
        float n0B[4] = {0.f, 0.f, 0.f, 0.f}, n1B[4] = {0.f, 0.f, 0.f, 0.f};
        float dnA[4] = {0.f, 0.f, 0.f, 0.f}, dnB[4] = {0.f, 0.f, 0.f, 0.f};

        float w0[8], w1[8], w2[8], wv0[8], wv1[8];

        auto acc_row = [&](const float (&c0)[4], const float (&c1)[4], const float (&c2)[4],
                           float (&n0)[4], float (&n1)[4], float (&dn)[4]) {
#pragma unroll
            for (int dx = 0; dx < 5; ++dx) {
#pragma unroll
                for (int px = 0; px < 4; ++px) {
                    const int k = dx + px;
                    const float d0 = c0[px] - w0[k];
                    const float d1 = c1[px] - w1[k];
                    const float d2 = c2[px] - w2[k];
                    const float id = fmaf(d0, d0, fmaf(d1, d1, d2 * d2));
                    const float coeff = fmaxf(fmaf(id, -SIDIV, 0.875f), 0.0f);
                    n0[px] = fmaf(wv0[k], coeff, n0[px]);
                    n1[px] = fmaf(wv1[k], coeff, n1[px]);
                    dn[px] += coeff;
                }
            }
        };

#pragma unroll
        for (int r = 0; r < 6; ++r) {
            const int hr = rA + r;
            const float4 a0 = *(const float4*)&smem[0][hr][lx];
            const float4 b0 = *(const float4*)&smem[0][hr][lx + 4];
            const float4 a1 = *(const float4*)&smem[1][hr][lx];
            const float4 b1 = *(const float4*)&smem[1][hr][lx + 4];
            const float4 a2 = *(const float4*)&smem[2][hr][lx];
            const float4 b2 = *(const float4*)&smem[2][hr][lx + 4];
            const float4 av0 = *(const float4*)&smem[3][hr][lx];
            const float4 bv0 = *(const float4*)&smem[3][hr][lx + 4];
            const float4 av1 = *(const float4*)&smem[4][hr][lx];
            const float4 bv1 = *(const float4*)&smem[4][hr][lx + 4];

            w0[0]=a0.x; w0[1]=a0.y; w0[2]=a0.z; w0[3]=a0.w; w0[4]=b0.x; w0[5]=b0.y; w0[6]=b0.z; w0[7]=b0.w;
            w1[0]=a1.x; w1[1]=a1.y; w1[2]=a1.z; w1[3]=a1.w; w1[4]=b1.x; w1[5]=b1.y; w1[6]=b1.z; w1[7]=b1.w;
            w2[0]=a2.x; w2[1]=a2.y; w2[2]=a2.z; w2[3]=a2.w; w2[4]=b2.x; w2[5]=b2.y; w2[6]=b2.z; w2[7]=b2.w;
            wv0[0]=av0.x; wv0[1]=av0.y; wv0[2]=av0.z; wv0[3]=av0.w; wv0[4]=bv0.x; wv0[5]=bv0.y; wv0[6]=bv0.z; wv0[7]=bv0.w;
            wv1[0]=av1.x; wv1[1]=av1.y; wv1[2]=av1.z; wv1[3]=av1.w; wv1[4]=bv1.x; wv1[5]=bv1.y; wv1[6]=bv1.z; wv1[7]=bv1.w;

            if (r < 5) acc_row(cA0, cA1, cA2, n0A, n1A, dnA);   // out row A, dy = r
            if (r > 0) acc_row(cB0, cB1, cB2, n0B, n1B, dnB);   // out row B, dy = r-1
        }

        const int gx  = x0 + lx;
        const int gyA = y0 + rA;      // <= 1078; gyA+1 <= 1079 (exact tiling, no mask)

        float4 oA0, oA1, oB0, oB1;
        {
            const float r0 = __builtin_amdgcn_rcpf(dnA[0]);
            const float r1 = __builtin_amdgcn_rcpf(dnA[1]);
            const float r2 = __builtin_amdgcn_rcpf(dnA[2]);
            const float r3 = __builtin_amdgcn_rcpf(dnA[3]);
            oA0.x = n0A[0] * r0; oA0.y = n0A[1] * r1; oA0.z = n0A[2] * r2; oA0.w = n0A[3] * r3;
            oA1.x = n1A[0] * r0; oA1.y = n1A[1] * r1; oA1.z = n1A[2] * r2; oA1.w = n1A[3] * r3;
        }
        {
            const float r0 = __builtin_amdgcn_rcpf(dnB[0]);
            const float r1 = __builtin_amdgcn_rcpf(dnB[1]);
            const float r2 = __builtin_amdgcn_rcpf(dnB[2]);
            const float r3 = __builtin_amdgcn_rcpf(dnB[3]);
            oB0.x = n0B[0] * r0; oB0.y = n0B[1] * r1; oB0.z = n0B[2] * r2; oB0.w = n0B[3] * r3;
            oB1.x = n1B[0] * r0; oB1.y = n1B[1] * r1; oB1.z = n1B[2] * r2; oB1.w = n1B[3] * r3;
        }

        *(float4*)(out + gyA * IMG_W + gx)                 = oA0;
        *(float4*)(out + IMG_HW + gyA * IMG_W + gx)        = oA1;
        *(float4*)(out + (gyA + 1) * IMG_W + gx)           = oB0;
        *(float4*)(out + IMG_HW + (gyA + 1) * IMG_W + gx)  = oB1;
    }
}

extern "C" void kernel_launch(void* const* d_in, const int* in_sizes, int n_in,
                              void* d_out, int out_size, void* d_ws, size_t ws_size,
                              hipStream_t stream) {
    const float* tpl = (const float*)d_in[0];
    const float* vec = (const float*)d_in[1];
    float* out = (float*)d_out;

    dim3 grid(IMG_W / TS_X, IMG_H / TS_Y);   // 30 x 36
    jbf_kernel<<<grid, 256, 0, stream>>>(tpl, vec, out);
}